// Round 7
// baseline (214.699 us; speedup 1.0000x reference)
//
#include <hip/hip_runtime.h>
#include <hip/hip_bf16.h>

typedef float f32x4 __attribute__((ext_vector_type(4)));
typedef __bf16 bf16x8 __attribute__((ext_vector_type(8)));

__device__ __forceinline__ unsigned short f2bf(float f) {
    unsigned u = __float_as_uint(f);
    return (unsigned short)((u + 0x7fffu + ((u >> 16) & 1u)) >> 16);  // RNE
}

// ---------------------------------------------------------------------------
// Fused prep: one dispatch.
//   blocks [0,1024):      x fp32 -> bf16 (2M elems, 8/thread)
//   blocks [1024,2304):   W1/W2 transpose+convert (64x64 tiles)
//   block  2304:          zero scores accumulator (4096 f32)
// ---------------------------------------------------------------------------
__global__ __launch_bounds__(256) void prep_all(
    const float* __restrict__ x, unsigned short* __restrict__ xb,
    const float* __restrict__ W1, unsigned short* __restrict__ W1t,
    const float* __restrict__ W2, unsigned short* __restrict__ W2t,
    float* __restrict__ sc)
{
    __shared__ float tile[64][65];
    const int bx = blockIdx.x;
    const int t = threadIdx.x;

    if (bx < 1024) {                       // convert x
        int i = bx * 2048 + t * 8;
        float4 v0 = *(const float4*)(x + i);
        float4 v1 = *(const float4*)(x + i + 4);
        ushort4 o0 = { f2bf(v0.x), f2bf(v0.y), f2bf(v0.z), f2bf(v0.w) };
        ushort4 o1 = { f2bf(v1.x), f2bf(v1.y), f2bf(v1.z), f2bf(v1.w) };
        *(ushort4*)(xb + i)     = o0;
        *(ushort4*)(xb + i + 4) = o1;
        return;
    }
    if (bx == 2304) {                      // zero scores
        float4 z = {0.f, 0.f, 0.f, 0.f};
        #pragma unroll
        for (int i = 0; i < 4; ++i)
            *(float4*)(sc + t * 16 + i * 4) = z;
        return;
    }
    // transpose tiles
    int idx = bx - 1024;
    int ty = idx >> 5;                     // 0..39
    int txi = idx & 31;                    // 0..31
    const float* W; unsigned short* Wt; int K, N, by;
    if (ty < 8) { W = W1; Wt = W1t; K = 512;  N = 2048; by = ty; }
    else        { W = W2; Wt = W2t; K = 2048; N = 2048; by = ty - 8; }

    const int col4 = t & 15;
    const int row  = t >> 4;
    #pragma unroll
    for (int i = 0; i < 4; ++i) {
        int r = row + i * 16;
        float4 v = *(const float4*)(W + (size_t)(by * 64 + r) * N + txi * 64 + col4 * 4);
        tile[r][col4 * 4 + 0] = v.x;
        tile[r][col4 * 4 + 1] = v.y;
        tile[r][col4 * 4 + 2] = v.z;
        tile[r][col4 * 4 + 3] = v.w;
    }
    __syncthreads();
    #pragma unroll
    for (int i = 0; i < 4; ++i) {
        int r = row + i * 16;
        ushort4 o = { f2bf(tile[col4 * 4 + 0][r]), f2bf(tile[col4 * 4 + 1][r]),
                      f2bf(tile[col4 * 4 + 2][r]), f2bf(tile[col4 * 4 + 3][r]) };
        *(ushort4*)(Wt + (size_t)(txi * 64 + r) * K + by * 64 + col4 * 4) = o;
    }
}

// ---------------------------------------------------------------------------
// bf16 MFMA GEMM, 64x128 tile (BM=64, BN=128, BK=32) -> grid 16x64 = 1024
// blocks = 4 blocks/CU for latency overlap (R6 showed 2/CU is the limiter).
// 256 threads = 4 waves; wave w computes 64x32 (wn = w*32): 4x2 frags of
// mfma_f32_16x16x32_bf16. XOR-swizzled LDS (R6: kills 8-way conflicts).
// MODE 0: C = relu(A@Bt^T+bias) bf16. MODE 1: fused layer-3 rank-1 epilogue.
// ---------------------------------------------------------------------------
template <int MODE>
__global__ __launch_bounds__(256, 4) void gemm_bf16_mfma(
    const unsigned short* __restrict__ A, const unsigned short* __restrict__ Bt,
    const float* __restrict__ bias, unsigned short* __restrict__ Cbf,
    const float* __restrict__ w3, float* __restrict__ scores,
    int M, int N, int K)
{
    __shared__ unsigned short As[64 * 32];    // 4 KB
    __shared__ unsigned short Bs[128 * 32];   // 8 KB

    const int tid = threadIdx.x;
    const int wave = tid >> 6;
    const int lane = tid & 63;
    const int bn = blockIdx.x, bm = blockIdx.y;
    const int wn = wave * 32;

    const unsigned short* Ablk = A  + (size_t)(bm * 64)  * K;
    const unsigned short* Bblk = Bt + (size_t)(bn * 128) * K;

    const int lrow = lane >> 2;                              // 0..15
    const int lcol = (((lane & 3) ^ ((lane >> 3) & 3))) * 8; // swizzled chunk

    f32x4 acc[4][2] = {};

    for (int k0 = 0; k0 < K; k0 += 32) {
        // A: wave stages rows [wave*16, +16); B: rows [wave*32, +32).
        {
            int ra = wave * 16 + lrow;
            __builtin_amdgcn_global_load_lds(
                (const __attribute__((address_space(1))) void*)(Ablk + (size_t)ra * K + k0 + lcol),
                (__attribute__((address_space(3))) void*)(As + (wave * 16) * 32),
                16, 0, 0);
            #pragma unroll
            for (int j = 0; j < 2; ++j) {
                int rb = wave * 32 + j * 16 + lrow;
                __builtin_amdgcn_global_load_lds(
                    (const __attribute__((address_space(1))) void*)(Bblk + (size_t)rb * K + k0 + lcol),
                    (__attribute__((address_space(3))) void*)(Bs + (wave * 32 + j * 16) * 32),
                    16, 0, 0);
            }
        }
        __syncthreads();

        const int rsw = (((lane >> 4) ^ ((lane >> 1) & 3))) * 8;
        bf16x8 a[4], b[2];
        #pragma unroll
        for (int mt = 0; mt < 4; ++mt)
            a[mt] = *(const bf16x8*)(As + (mt * 16 + (lane & 15)) * 32 + rsw);
        #pragma unroll
        for (int nt = 0; nt < 2; ++nt)
            b[nt] = *(const bf16x8*)(Bs + (wn + nt * 16 + (lane & 15)) * 32 + rsw);
        #pragma unroll
        for (int mt = 0; mt < 4; ++mt)
            #pragma unroll
            for (int nt = 0; nt < 2; ++nt)
                acc[mt][nt] = __builtin_amdgcn_mfma_f32_16x16x32_bf16(
                    a[mt], b[nt], acc[mt][nt], 0, 0, 0);
        __syncthreads();
    }

    // Epilogue. C/D frag: col = lane&15, row = (lane>>4)*4 + reg  [m89]
    const int cm0 = bm * 64;
    const int cn0 = bn * 128 + wn;
    const int lc = lane & 15;
    const int lr = (lane >> 4) * 4;

    if (MODE == 0) {
        #pragma unroll
        for (int nt = 0; nt < 2; ++nt) {
            float bv = bias[cn0 + nt * 16 + lc];
            #pragma unroll
            for (int mt = 0; mt < 4; ++mt) {
                #pragma unroll
                for (int r = 0; r < 4; ++r) {
                    float v = fmaxf(acc[mt][nt][r] + bv, 0.0f);
                    size_t idx = (size_t)(cm0 + mt * 16 + lr + r) * N + cn0 + nt * 16 + lc;
                    Cbf[idx] = f2bf(v);
                }
            }
        }
    } else {
        float bv[2], w3v[2];
        #pragma unroll
        for (int nt = 0; nt < 2; ++nt) {
            bv[nt]  = bias[cn0 + nt * 16 + lc];
            w3v[nt] = w3[cn0 + nt * 16 + lc];
        }
        #pragma unroll
        for (int mt = 0; mt < 4; ++mt) {
            #pragma unroll
            for (int r = 0; r < 4; ++r) {
                float p = 0.0f;
                #pragma unroll
                for (int nt = 0; nt < 2; ++nt)
                    p += fmaxf(acc[mt][nt][r] + bv[nt], 0.0f) * w3v[nt];
                p += __shfl_xor(p, 1);
                p += __shfl_xor(p, 2);
                p += __shfl_xor(p, 4);
                p += __shfl_xor(p, 8);
                if (lc == 0)
                    atomicAdd(&scores[cm0 + mt * 16 + lr + r], p);
            }
        }
    }
}

// ---------------------------------------------------------------------------
// Fused finalize + rank count. Grid 16 x 1024 threads.
// Each block builds ALL 4096 keys in LDS from sc+b3 (distinct keys:
// (desc_map << 12) | i, stable descending ties->index asc), then counts
// pos for its 256 i's: 4 j-chunks of 1024 per i, LDS partial reduce,
// direct store to posg (no atomics, no memset). Block 0 writes out_scores.
// ---------------------------------------------------------------------------
__global__ __launch_bounds__(1024) void rank_keys(
    const float* __restrict__ sc, const float* __restrict__ b3,
    float* __restrict__ out_scores, int* __restrict__ posg)
{
    constexpr int n = 4096;
    __shared__ unsigned long long keys[n];   // 32 KB
    __shared__ int partial[4][256];          // 4 KB
    const int tid = threadIdx.x;
    const int bi = blockIdx.x;
    const float b3v = b3[0];

    for (int t = tid; t < n; t += 1024) {
        float v = sc[t] + b3v;
        if (bi == 0) out_scores[t] = v;
        unsigned ub = __float_as_uint(v);
        unsigned m  = (ub & 0x80000000u) ? ~ub : (ub | 0x80000000u); // asc map
        unsigned d  = ~m;                                            // desc map
        keys[t] = ((unsigned long long)d << 12) | (unsigned)t;
    }
    __syncthreads();

    const int li = tid & 255;
    const int jc = tid >> 8;
    const unsigned long long mykey = keys[bi * 256 + li];
    int cnt = 0;
    #pragma unroll 16
    for (int j = jc * 1024; j < (jc + 1) * 1024; ++j)
        cnt += (keys[j] < mykey) ? 1 : 0;
    partial[jc][li] = cnt;
    __syncthreads();
    if (tid < 256)
        posg[bi * 256 + tid] = partial[0][tid] + partial[1][tid] +
                               partial[2][tid] + partial[3][tid];
}

// ---------------------------------------------------------------------------
// PAV + fill, single block of 1024 threads (chunked PAV, verified R2-R6).
// svals[pos[i]] = sc[i]+b3 -> chunk PAV (64x64) -> serial merge -> gather.
// ---------------------------------------------------------------------------
__global__ __launch_bounds__(1024) void pav_fill(
    const float* __restrict__ scores, const float* __restrict__ b3,
    const int* __restrict__ posg, float* __restrict__ rank_out, int* nb_ws)
{
    constexpr int n = 4096;
    __shared__ __align__(16) unsigned char lds[65536];
    double* bsum  = (double*)lds;
    float*  svals = (float*)(lds + 32768);
    unsigned short* bstart = (unsigned short*)(lds + 49152);
    unsigned short* plds   = (unsigned short*)(lds + 57344);

    const int tid = threadIdx.x;
    const float b3v = b3[0];

    for (int t = tid; t < n; t += 1024) {
        int p = posg[t];
        svals[p] = scores[t] + b3v;
        plds[t] = (unsigned short)p;
    }
    __syncthreads();

    // ---- Phase A: per-chunk PAV, 64 threads, chunk c = tid ----
    if (tid < 64) {
        const int base = tid << 6;
        int depth = 0;
        double rtsum = 0.0; int rtstart = 0;
        for (int s = 0; s < 64; ++s) {
            int i = base + s;
            double csum = (double)svals[i] - (double)(n - i);   // y_i
            int cs = i;
            const int ce = i + 1;
            while (depth > 0) {
                if (rtsum * (double)(ce - cs) <= csum * (double)(cs - rtstart)) {
                    csum += rtsum; cs = rtstart; depth--;
                    if (depth > 0) {
                        rtsum = bsum[base + depth - 1];
                        rtstart = bstart[base + depth - 1];
                    }
                } else break;
            }
            if (depth > 0) {
                bsum[base + depth - 1] = rtsum;
                bstart[base + depth - 1] = (unsigned short)rtstart;
            }
            rtsum = csum; rtstart = cs; depth++;
        }
        bsum[base + depth - 1] = rtsum;
        bstart[base + depth - 1] = (unsigned short)rtstart;
        if (depth < 64) bstart[base + depth] = 0xFFFFu;   // sentinel
    }
    __syncthreads();

    // ---- Phase B: serial merge of chunk block lists (thread 0) ----
    if (tid == 0) {
        int g = 0;
        double gtsum = 0.0; int gtstart = 0;
        for (int c = 0; c < 64; ++c) {
            const int base = c << 6;
            for (int s = 0; s < 64; ++s) {
                const int r = base + s;
                int cs = bstart[r];
                if (cs == 0xFFFF) break;
                int ce;
                if (s < 63) {
                    int nx = bstart[r + 1];
                    ce = (nx == 0xFFFF) ? base + 64 : nx;
                } else ce = base + 64;
                double csum = bsum[r];
                while (g > 0) {
                    if (gtsum * (double)(ce - cs) <= csum * (double)(cs - gtstart)) {
                        csum += gtsum; cs = gtstart; g--;
                        if (g > 0) { gtsum = bsum[g - 1]; gtstart = bstart[g - 1]; }
                    } else break;
                }
                if (g > 0) {
                    bsum[g - 1] = gtsum;
                    bstart[g - 1] = (unsigned short)gtstart;
                }
                gtsum = csum; gtstart = cs; g++;
            }
        }
        bsum[g - 1] = gtsum;
        bstart[g - 1] = (unsigned short)gtstart;
        __hip_atomic_store(nb_ws, g, __ATOMIC_RELEASE, __HIP_MEMORY_SCOPE_AGENT);
    }
    __syncthreads();
    const int nb = __hip_atomic_load(nb_ws, __ATOMIC_ACQUIRE, __HIP_MEMORY_SCOPE_AGENT);

    // ---- gather: rank[i] = svals[p] - mean(block(p)), coalesced writes ----
    for (int t = tid; t < n; t += 1024) {
        int p = plds[t];
        int lo = 0, hi = nb - 1;
        while (lo < hi) {
            int mid = (lo + hi + 1) >> 1;
            if ((int)bstart[mid] <= p) lo = mid; else hi = mid - 1;
        }
        int bs = bstart[lo];
        int be = (lo + 1 < nb) ? (int)bstart[lo + 1] : n;
        float mean = (float)(bsum[lo] / (double)(be - bs));
        rank_out[t] = svals[p] - mean;
    }
}

// ---------------------------------------------------------------------------
extern "C" void kernel_launch(void* const* d_in, const int* in_sizes, int n_in,
                              void* d_out, int out_size, void* d_ws, size_t ws_size,
                              hipStream_t stream) {
    const float* x  = (const float*)d_in[0];
    const float* W1 = (const float*)d_in[1];
    const float* b1 = (const float*)d_in[2];
    const float* W2 = (const float*)d_in[3];
    const float* b2 = (const float*)d_in[4];
    const float* W3 = (const float*)d_in[5];
    const float* b3 = (const float*)d_in[6];
    float* out = (float*)d_out;   // [0,4096): rank, [4096,8192): scores

    const int B = 4096, D_IN = 512, H = 2048;

    char* ws = (char*)d_ws;
    unsigned short* h1  = (unsigned short*)(ws);                    // 16 MB bf16
    unsigned short* xb  = (unsigned short*)(ws + (16u << 20));      //  4 MB bf16
    unsigned short* W1t = (unsigned short*)(ws + (20u << 20));      //  2 MB bf16 [N,K]
    unsigned short* W2t = (unsigned short*)(ws + (22u << 20));      //  8 MB bf16 [N,K]
    float*          sc  = (float*)(ws + (30u << 20));               // 16 KB
    int*            posg= (int*)(ws + (30u << 20) + 16384);         // 16 KB
    int*            nb  = (int*)(ws + (30u << 20) + 32768);

    // 1) fused prep: convert x, transpose W1/W2, zero sc.
    prep_all<<<2305, 256, 0, stream>>>(x, xb, W1, W1t, W2, W2t, sc);

    // 2) GEMM1: h1 = relu(x @ W1 + b1), bf16. M=4096 N=2048 K=512.
    gemm_bf16_mfma<0><<<dim3(H / 128, B / 64), 256, 0, stream>>>(
        xb, W1t, b1, h1, nullptr, nullptr, B, H, D_IN);
    // 3) GEMM2 fused with layer-3: scores += relu(h1@W2+b2) @ W3.
    gemm_bf16_mfma<1><<<dim3(H / 128, B / 64), 256, 0, stream>>>(
        h1, W2t, b2, nullptr, W3, sc, B, H, H);

    // 4) finalize + rank count (keys in LDS, no atomics).
    rank_keys<<<16, 1024, 0, stream>>>(sc, b3, out + B, posg);
    // 5) PAV + fill.
    pav_fill<<<1, 1024, 0, stream>>>(sc, b3, posg, out, nb);
}

// Round 9
// 208.108 us; speedup vs baseline: 1.0317x; 1.0317x over previous
//
#include <hip/hip_runtime.h>
#include <hip/hip_bf16.h>

typedef float f32x4 __attribute__((ext_vector_type(4)));
typedef __bf16 bf16x8 __attribute__((ext_vector_type(8)));

__device__ __forceinline__ unsigned short f2bf(float f) {
    unsigned u = __float_as_uint(f);
    return (unsigned short)((u + 0x7fffu + ((u >> 16) & 1u)) >> 16);  // RNE
}

// ---------------------------------------------------------------------------
// Fused prep: one dispatch.
//   blocks [0,1024):      x fp32 -> bf16 (2M elems, 8/thread)
//   blocks [1024,2304):   W1/W2 transpose+convert (64x64 tiles)
//   block  2304:          zero scores accumulator (4096 f32)
// ---------------------------------------------------------------------------
__global__ __launch_bounds__(256) void prep_all(
    const float* __restrict__ x, unsigned short* __restrict__ xb,
    const float* __restrict__ W1, unsigned short* __restrict__ W1t,
    const float* __restrict__ W2, unsigned short* __restrict__ W2t,
    float* __restrict__ sc)
{
    __shared__ float tile[64][65];
    const int bx = blockIdx.x;
    const int t = threadIdx.x;

    if (bx < 1024) {                       // convert x
        int i = bx * 2048 + t * 8;
        float4 v0 = *(const float4*)(x + i);
        float4 v1 = *(const float4*)(x + i + 4);
        ushort4 o0 = { f2bf(v0.x), f2bf(v0.y), f2bf(v0.z), f2bf(v0.w) };
        ushort4 o1 = { f2bf(v1.x), f2bf(v1.y), f2bf(v1.z), f2bf(v1.w) };
        *(ushort4*)(xb + i)     = o0;
        *(ushort4*)(xb + i + 4) = o1;
        return;
    }
    if (bx == 2304) {                      // zero scores
        float4 z = {0.f, 0.f, 0.f, 0.f};
        #pragma unroll
        for (int i = 0; i < 4; ++i)
            *(float4*)(sc + t * 16 + i * 4) = z;
        return;
    }
    // transpose tiles
    int idx = bx - 1024;
    int ty = idx >> 5;                     // 0..39
    int txi = idx & 31;                    // 0..31
    const float* W; unsigned short* Wt; int K, N, by;
    if (ty < 8) { W = W1; Wt = W1t; K = 512;  N = 2048; by = ty; }
    else        { W = W2; Wt = W2t; K = 2048; N = 2048; by = ty - 8; }

    const int col4 = t & 15;
    const int row  = t >> 4;
    #pragma unroll
    for (int i = 0; i < 4; ++i) {
        int r = row + i * 16;
        float4 v = *(const float4*)(W + (size_t)(by * 64 + r) * N + txi * 64 + col4 * 4);
        tile[r][col4 * 4 + 0] = v.x;
        tile[r][col4 * 4 + 1] = v.y;
        tile[r][col4 * 4 + 2] = v.z;
        tile[r][col4 * 4 + 3] = v.w;
    }
    __syncthreads();
    #pragma unroll
    for (int i = 0; i < 4; ++i) {
        int r = row + i * 16;
        ushort4 o = { f2bf(tile[col4 * 4 + 0][r]), f2bf(tile[col4 * 4 + 1][r]),
                      f2bf(tile[col4 * 4 + 2][r]), f2bf(tile[col4 * 4 + 3][r]) };
        *(ushort4*)(Wt + (size_t)(txi * 64 + r) * K + by * 64 + col4 * 4) = o;
    }
}

// ---------------------------------------------------------------------------
// bf16 MFMA GEMM, 64x128 tile, BK=64 (halve barrier-drain count — R7
// showed occupancy is NOT the binder; the per-iter vmcnt(0)+barrier drain is).
// LDS 24 KB, 4 blocks/CU. 256 threads = 4 waves; wave w computes 64x32.
// Swizzle (8 chunks/row of 16B): LDS(r,c) = global(r, c ^ (r&7)); per
// quarter-wave phase each chunk value gets 2 lanes 1024B apart (same banks,
// 2-way = free), full 32-bank coverage; all address terms lane-only.
// MODE 0: C = relu(A@Bt^T+bias) bf16. MODE 1: fused layer-3 rank-1 epilogue.
// ---------------------------------------------------------------------------
template <int MODE>
__global__ __launch_bounds__(256, 4) void gemm_bf16_mfma(
    const unsigned short* __restrict__ A, const unsigned short* __restrict__ Bt,
    const float* __restrict__ bias, unsigned short* __restrict__ Cbf,
    const float* __restrict__ w3, float* __restrict__ scores,
    int M, int N, int K)
{
    __shared__ unsigned short As[64 * 64];    // 8 KB
    __shared__ unsigned short Bs[128 * 64];   // 16 KB

    const int tid = threadIdx.x;
    const int wave = tid >> 6;
    const int lane = tid & 63;
    const int bn = blockIdx.x, bm = blockIdx.y;
    const int wn = wave * 32;

    const unsigned short* Ablk = A  + (size_t)(bm * 64)  * K;
    const unsigned short* Bblk = Bt + (size_t)(bn * 128) * K;

    // staging: each inst covers 8 rows (8 x 128B = 1KB); lane L -> row
    // r0+(L>>3), swizzled global chunk (L&7)^(L>>3).
    const int rl   = lane >> 3;                       // 0..7
    const int gch  = ((lane & 7) ^ rl) * 8;           // element offset

    f32x4 acc[4][2] = {};

    for (int k0 = 0; k0 < K; k0 += 64) {
        {
            #pragma unroll
            for (int s2 = 0; s2 < 2; ++s2) {          // A rows [wave*16,+16)
                int r0 = wave * 16 + s2 * 8;
                __builtin_amdgcn_global_load_lds(
                    (const __attribute__((address_space(1))) void*)(Ablk + (size_t)(r0 + rl) * K + k0 + gch),
                    (__attribute__((address_space(3))) void*)(As + r0 * 64),
                    16, 0, 0);
            }
            #pragma unroll
            for (int s2 = 0; s2 < 4; ++s2) {          // B rows [wave*32,+32)
                int r0 = wave * 32 + s2 * 8;
                __builtin_amdgcn_global_load_lds(
                    (const __attribute__((address_space(1))) void*)(Bblk + (size_t)(r0 + rl) * K + k0 + gch),
                    (__attribute__((address_space(3))) void*)(Bs + r0 * 64),
                    16, 0, 0);
            }
        }
        __syncthreads();

        #pragma unroll
        for (int s = 0; s < 2; ++s) {                 // two 16x16x32 k-steps
            const int rsw = ((s * 4 + (lane >> 4)) ^ (lane & 7)) * 8;
            bf16x8 a[4], b[2];
            #pragma unroll
            for (int mt = 0; mt < 4; ++mt)
                a[mt] = *(const bf16x8*)(As + (mt * 16 + (lane & 15)) * 64 + rsw);
            #pragma unroll
            for (int nt = 0; nt < 2; ++nt)
                b[nt] = *(const bf16x8*)(Bs + (wn + nt * 16 + (lane & 15)) * 64 + rsw);
            #pragma unroll
            for (int mt = 0; mt < 4; ++mt)
                #pragma unroll
                for (int nt = 0; nt < 2; ++nt)
                    acc[mt][nt] = __builtin_amdgcn_mfma_f32_16x16x32_bf16(
                        a[mt], b[nt], acc[mt][nt], 0, 0, 0);
        }
        __syncthreads();
    }

    // Epilogue. C/D frag: col = lane&15, row = (lane>>4)*4 + reg  [m89]
    const int cm0 = bm * 64;
    const int cn0 = bn * 128 + wn;
    const int lc = lane & 15;
    const int lr = (lane >> 4) * 4;

    if (MODE == 0) {
        #pragma unroll
        for (int nt = 0; nt < 2; ++nt) {
            float bv = bias[cn0 + nt * 16 + lc];
            #pragma unroll
            for (int mt = 0; mt < 4; ++mt) {
                #pragma unroll
                for (int r = 0; r < 4; ++r) {
                    float v = fmaxf(acc[mt][nt][r] + bv, 0.0f);
                    size_t idx = (size_t)(cm0 + mt * 16 + lr + r) * N + cn0 + nt * 16 + lc;
                    Cbf[idx] = f2bf(v);
                }
            }
        }
    } else {
        float bv[2], w3v[2];
        #pragma unroll
        for (int nt = 0; nt < 2; ++nt) {
            bv[nt]  = bias[cn0 + nt * 16 + lc];
            w3v[nt] = w3[cn0 + nt * 16 + lc];
        }
        #pragma unroll
        for (int mt = 0; mt < 4; ++mt) {
            #pragma unroll
            for (int r = 0; r < 4; ++r) {
                float p = 0.0f;
                #pragma unroll
                for (int nt = 0; nt < 2; ++nt)
                    p += fmaxf(acc[mt][nt][r] + bv[nt], 0.0f) * w3v[nt];
                p += __shfl_xor(p, 1);
                p += __shfl_xor(p, 2);
                p += __shfl_xor(p, 4);
                p += __shfl_xor(p, 8);
                if (lc == 0)
                    atomicAdd(&scores[cm0 + mt * 16 + lr + r], p);
            }
        }
    }
}

// ---------------------------------------------------------------------------
// Fused finalize + rank count. Grid 16 x 1024 threads.
// ---------------------------------------------------------------------------
__global__ __launch_bounds__(1024) void rank_keys(
    const float* __restrict__ sc, const float* __restrict__ b3,
    float* __restrict__ out_scores, int* __restrict__ posg)
{
    constexpr int n = 4096;
    __shared__ unsigned long long keys[n];   // 32 KB
    __shared__ int partial[4][256];          // 4 KB
    const int tid = threadIdx.x;
    const int bi = blockIdx.x;
    const float b3v = b3[0];

    for (int t = tid; t < n; t += 1024) {
        float v = sc[t] + b3v;
        if (bi == 0) out_scores[t] = v;
        unsigned ub = __float_as_uint(v);
        unsigned m  = (ub & 0x80000000u) ? ~ub : (ub | 0x80000000u); // asc map
        unsigned d  = ~m;                                            // desc map
        keys[t] = ((unsigned long long)d << 12) | (unsigned)t;
    }
    __syncthreads();

    const int li = tid & 255;
    const int jc = tid >> 8;
    const unsigned long long mykey = keys[bi * 256 + li];
    int cnt = 0;
    #pragma unroll 16
    for (int j = jc * 1024; j < (jc + 1) * 1024; ++j)
        cnt += (keys[j] < mykey) ? 1 : 0;
    partial[jc][li] = cnt;
    __syncthreads();
    if (tid < 256)
        posg[bi * 256 + tid] = partial[0][tid] + partial[1][tid] +
                               partial[2][tid] + partial[3][tid];
}

// ---------------------------------------------------------------------------
// PAV + fill, single block of 1024 threads (chunked PAV, verified R2-R7).
// ---------------------------------------------------------------------------
__global__ __launch_bounds__(1024) void pav_fill(
    const float* __restrict__ scores, const float* __restrict__ b3,
    const int* __restrict__ posg, float* __restrict__ rank_out, int* nb_ws)
{
    constexpr int n = 4096;
    __shared__ __align__(16) unsigned char lds[65536];
    double* bsum  = (double*)lds;
    float*  svals = (float*)(lds + 32768);
    unsigned short* bstart = (unsigned short*)(lds + 49152);
    unsigned short* plds   = (unsigned short*)(lds + 57344);

    const int tid = threadIdx.x;
    const float b3v = b3[0];

    for (int t = tid; t < n; t += 1024) {
        int p = posg[t];
        svals[p] = scores[t] + b3v;
        plds[t] = (unsigned short)p;
    }
    __syncthreads();

    // ---- Phase A: per-chunk PAV, 64 threads, chunk c = tid ----
    if (tid < 64) {
        const int base = tid << 6;
        int depth = 0;
        double rtsum = 0.0; int rtstart = 0;
        for (int s = 0; s < 64; ++s) {
            int i = base + s;
            double csum = (double)svals[i] - (double)(n - i);   // y_i
            int cs = i;
            const int ce = i + 1;
            while (depth > 0) {
                if (rtsum * (double)(ce - cs) <= csum * (double)(cs - rtstart)) {
                    csum += rtsum; cs = rtstart; depth--;
                    if (depth > 0) {
                        rtsum = bsum[base + depth - 1];
                        rtstart = bstart[base + depth - 1];
                    }
                } else break;
            }
            if (depth > 0) {
                bsum[base + depth - 1] = rtsum;
                bstart[base + depth - 1] = (unsigned short)rtstart;
            }
            rtsum = csum; rtstart = cs; depth++;
        }
        bsum[base + depth - 1] = rtsum;
        bstart[base + depth - 1] = (unsigned short)rtstart;
        if (depth < 64) bstart[base + depth] = 0xFFFFu;   // sentinel
    }
    __syncthreads();

    // ---- Phase B: serial merge of chunk block lists (thread 0) ----
    if (tid == 0) {
        int g = 0;
        double gtsum = 0.0; int gtstart = 0;
        for (int c = 0; c < 64; ++c) {
            const int base = c << 6;
            for (int s = 0; s < 64; ++s) {
                const int r = base + s;
                int cs = bstart[r];
                if (cs == 0xFFFF) break;
                int ce;
                if (s < 63) {
                    int nx = bstart[r + 1];
                    ce = (nx == 0xFFFF) ? base + 64 : nx;
                } else ce = base + 64;
                double csum = bsum[r];
                while (g > 0) {
                    if (gtsum * (double)(ce - cs) <= csum * (double)(cs - gtstart)) {
                        csum += gtsum; cs = gtstart; g--;
                        if (g > 0) { gtsum = bsum[g - 1]; gtstart = bstart[g - 1]; }
                    } else break;
                }
                if (g > 0) {
                    bsum[g - 1] = gtsum;
                    bstart[g - 1] = (unsigned short)gtstart;
                }
                gtsum = csum; gtstart = cs; g++;
            }
        }
        bsum[g - 1] = gtsum;
        bstart[g - 1] = (unsigned short)gtstart;
        __hip_atomic_store(nb_ws, g, __ATOMIC_RELEASE, __HIP_MEMORY_SCOPE_AGENT);
    }
    __syncthreads();
    const int nb = __hip_atomic_load(nb_ws, __ATOMIC_ACQUIRE, __HIP_MEMORY_SCOPE_AGENT);

    // ---- gather: rank[i] = svals[p] - mean(block(p)), coalesced writes ----
    for (int t = tid; t < n; t += 1024) {
        int p = plds[t];
        int lo = 0, hi = nb - 1;
        while (lo < hi) {
            int mid = (lo + hi + 1) >> 1;
            if ((int)bstart[mid] <= p) lo = mid; else hi = mid - 1;
        }
        int bs = bstart[lo];
        int be = (lo + 1 < nb) ? (int)bstart[lo + 1] : n;
        float mean = (float)(bsum[lo] / (double)(be - bs));
        rank_out[t] = svals[p] - mean;
    }
}

// ---------------------------------------------------------------------------
extern "C" void kernel_launch(void* const* d_in, const int* in_sizes, int n_in,
                              void* d_out, int out_size, void* d_ws, size_t ws_size,
                              hipStream_t stream) {
    const float* x  = (const float*)d_in[0];
    const float* W1 = (const float*)d_in[1];
    const float* b1 = (const float*)d_in[2];
    const float* W2 = (const float*)d_in[3];
    const float* b2 = (const float*)d_in[4];
    const float* W3 = (const float*)d_in[5];
    const float* b3 = (const float*)d_in[6];
    float* out = (float*)d_out;   // [0,4096): rank, [4096,8192): scores

    const int B = 4096, D_IN = 512, H = 2048;

    char* ws = (char*)d_ws;
    unsigned short* h1  = (unsigned short*)(ws);                    // 16 MB bf16
    unsigned short* xb  = (unsigned short*)(ws + (16u << 20));      //  4 MB bf16
    unsigned short* W1t = (unsigned short*)(ws + (20u << 20));      //  2 MB bf16 [N,K]
    unsigned short* W2t = (unsigned short*)(ws + (22u << 20));      //  8 MB bf16 [N,K]
    float*          sc  = (float*)(ws + (30u << 20));               // 16 KB
    int*            posg= (int*)(ws + (30u << 20) + 16384);         // 16 KB
    int*            nb  = (int*)(ws + (30u << 20) + 32768);

    // 1) fused prep: convert x, transpose W1/W2, zero sc.
    prep_all<<<2305, 256, 0, stream>>>(x, xb, W1, W1t, W2, W2t, sc);

    // 2) GEMM1: h1 = relu(x @ W1 + b1), bf16. M=4096 N=2048 K=512.
    gemm_bf16_mfma<0><<<dim3(H / 128, B / 64), 256, 0, stream>>>(
        xb, W1t, b1, h1, nullptr, nullptr, B, H, D_IN);
    // 3) GEMM2 fused with layer-3: scores += relu(h1@W2+b2) @ W3.
    gemm_bf16_mfma<1><<<dim3(H / 128, B / 64), 256, 0, stream>>>(
        h1, W2t, b2, nullptr, W3, sc, B, H, H);

    // 4) finalize + rank count (keys in LDS, no atomics).
    rank_keys<<<16, 1024, 0, stream>>>(sc, b3, out + B, posg);
    // 5) PAV + fill.
    pav_fill<<<1, 1024, 0, stream>>>(sc, b3, posg, out, nb);
}

// Round 10
// 182.997 us; speedup vs baseline: 1.1732x; 1.1372x over previous
//
#include <hip/hip_runtime.h>
#include <hip/hip_bf16.h>

typedef float f32x4 __attribute__((ext_vector_type(4)));
typedef __bf16 bf16x8 __attribute__((ext_vector_type(8)));

__device__ __forceinline__ unsigned short f2bf(float f) {
    unsigned u = __float_as_uint(f);
    return (unsigned short)((u + 0x7fffu + ((u >> 16) & 1u)) >> 16);  // RNE
}

__device__ __forceinline__ unsigned long long sort_key(float v, int idx) {
    unsigned ub = __float_as_uint(v);
    unsigned m  = (ub & 0x80000000u) ? ~ub : (ub | 0x80000000u);  // asc map
    return ((unsigned long long)(~m) << 12) | (unsigned)idx;      // desc, stable
}

// ---------------------------------------------------------------------------
// Fused prep: one dispatch.
//   blocks [0,1024):      x fp32 -> bf16
//   blocks [1024,2304):   W1/W2 transpose+convert (64x64 tiles)
//   block  2304:          zero scores accumulator + posg
// ---------------------------------------------------------------------------
__global__ __launch_bounds__(256) void prep_all(
    const float* __restrict__ x, unsigned short* __restrict__ xb,
    const float* __restrict__ W1, unsigned short* __restrict__ W1t,
    const float* __restrict__ W2, unsigned short* __restrict__ W2t,
    float* __restrict__ sc, int* __restrict__ posg)
{
    __shared__ float tile[64][65];
    const int bx = blockIdx.x;
    const int t = threadIdx.x;

    if (bx < 1024) {                       // convert x
        int i = bx * 2048 + t * 8;
        float4 v0 = *(const float4*)(x + i);
        float4 v1 = *(const float4*)(x + i + 4);
        ushort4 o0 = { f2bf(v0.x), f2bf(v0.y), f2bf(v0.z), f2bf(v0.w) };
        ushort4 o1 = { f2bf(v1.x), f2bf(v1.y), f2bf(v1.z), f2bf(v1.w) };
        *(ushort4*)(xb + i)     = o0;
        *(ushort4*)(xb + i + 4) = o1;
        return;
    }
    if (bx == 2304) {                      // zero sc + posg
        float4 z = {0.f, 0.f, 0.f, 0.f};
        int4 zi = {0, 0, 0, 0};
        #pragma unroll
        for (int i = 0; i < 4; ++i) {
            *(float4*)(sc + t * 16 + i * 4)  = z;
            *(int4*)(posg + t * 16 + i * 4)  = zi;
        }
        return;
    }
    // transpose tiles
    int idx = bx - 1024;
    int ty = idx >> 5;                     // 0..39
    int txi = idx & 31;                    // 0..31
    const float* W; unsigned short* Wt; int K, N, by;
    if (ty < 8) { W = W1; Wt = W1t; K = 512;  N = 2048; by = ty; }
    else        { W = W2; Wt = W2t; K = 2048; N = 2048; by = ty - 8; }

    const int col4 = t & 15;
    const int row  = t >> 4;
    #pragma unroll
    for (int i = 0; i < 4; ++i) {
        int r = row + i * 16;
        float4 v = *(const float4*)(W + (size_t)(by * 64 + r) * N + txi * 64 + col4 * 4);
        tile[r][col4 * 4 + 0] = v.x;
        tile[r][col4 * 4 + 1] = v.y;
        tile[r][col4 * 4 + 2] = v.z;
        tile[r][col4 * 4 + 3] = v.w;
    }
    __syncthreads();
    #pragma unroll
    for (int i = 0; i < 4; ++i) {
        int r = row + i * 16;
        ushort4 o = { f2bf(tile[col4 * 4 + 0][r]), f2bf(tile[col4 * 4 + 1][r]),
                      f2bf(tile[col4 * 4 + 2][r]), f2bf(tile[col4 * 4 + 3][r]) };
        *(ushort4*)(Wt + (size_t)(txi * 64 + r) * K + by * 64 + col4 * 4) = o;
    }
}

// ---------------------------------------------------------------------------
// bf16 MFMA GEMM, 128x128 tile, BK=64, 512 threads = 8 waves (2x4: wm 2x64,
// wn 4x32). R10: staging traffic is the binder (R9: 768 MB staged at ~57
// B/cyc/CU); 128-square reuse cuts it to 512 MB at unchanged 16 waves/CU.
// LDS 32 KB, grid 512 = 2 blocks/CU. Swizzle: LDS(r,c)=global(r, c^(r&7)),
// c = 16B chunk (8 per BK=64 row); 2-way bank aliasing only (free), all
// address terms lane-only. Verified 0 conflicts in R9.
// MODE 0: C = relu(A@Bt^T+bias) bf16. MODE 1: fused layer-3 rank-1 epilogue.
// ---------------------------------------------------------------------------
template <int MODE>
__global__ __launch_bounds__(512, 4) void gemm_bf16_mfma(
    const unsigned short* __restrict__ A, const unsigned short* __restrict__ Bt,
    const float* __restrict__ bias, unsigned short* __restrict__ Cbf,
    const float* __restrict__ w3, float* __restrict__ scores,
    int M, int N, int K)
{
    __shared__ unsigned short As[128 * 64];   // 16 KB
    __shared__ unsigned short Bs[128 * 64];   // 16 KB

    const int tid = threadIdx.x;
    const int wave = tid >> 6;                // 0..7
    const int lane = tid & 63;
    const int bn = blockIdx.x, bm = blockIdx.y;
    const int wm = (wave & 1) * 64;
    const int wn = (wave >> 1) * 32;

    const unsigned short* Ablk = A  + (size_t)(bm * 128) * K;
    const unsigned short* Bblk = Bt + (size_t)(bn * 128) * K;

    // staging: each inst covers 8 rows (1 KB); lane L -> row r0+(L>>3),
    // swizzled global chunk (L&7)^(L>>3).
    const int rl   = lane >> 3;                       // 0..7
    const int gch  = ((lane & 7) ^ rl) * 8;           // element offset

    f32x4 acc[4][2] = {};

    for (int k0 = 0; k0 < K; k0 += 64) {
        #pragma unroll
        for (int s2 = 0; s2 < 2; ++s2) {              // wave stages A+B rows [wave*16,+16)
            int r0 = wave * 16 + s2 * 8;
            __builtin_amdgcn_global_load_lds(
                (const __attribute__((address_space(1))) void*)(Ablk + (size_t)(r0 + rl) * K + k0 + gch),
                (__attribute__((address_space(3))) void*)(As + r0 * 64),
                16, 0, 0);
            __builtin_amdgcn_global_load_lds(
                (const __attribute__((address_space(1))) void*)(Bblk + (size_t)(r0 + rl) * K + k0 + gch),
                (__attribute__((address_space(3))) void*)(Bs + r0 * 64),
                16, 0, 0);
        }
        __syncthreads();

        #pragma unroll
        for (int s = 0; s < 2; ++s) {                 // two 16x16x32 k-steps
            const int rsw = ((s * 4 + (lane >> 4)) ^ (lane & 7)) * 8;
            bf16x8 a[4], b[2];
            #pragma unroll
            for (int mt = 0; mt < 4; ++mt)
                a[mt] = *(const bf16x8*)(As + (wm + mt * 16 + (lane & 15)) * 64 + rsw);
            #pragma unroll
            for (int nt = 0; nt < 2; ++nt)
                b[nt] = *(const bf16x8*)(Bs + (wn + nt * 16 + (lane & 15)) * 64 + rsw);
            #pragma unroll
            for (int mt = 0; mt < 4; ++mt)
                #pragma unroll
                for (int nt = 0; nt < 2; ++nt)
                    acc[mt][nt] = __builtin_amdgcn_mfma_f32_16x16x32_bf16(
                        a[mt], b[nt], acc[mt][nt], 0, 0, 0);
        }
        __syncthreads();
    }

    // Epilogue. C/D frag: col = lane&15, row = (lane>>4)*4 + reg  [m89]
    const int cm0 = bm * 128 + wm;
    const int cn0 = bn * 128 + wn;
    const int lc = lane & 15;
    const int lr = (lane >> 4) * 4;

    if (MODE == 0) {
        #pragma unroll
        for (int nt = 0; nt < 2; ++nt) {
            float bv = bias[cn0 + nt * 16 + lc];
            #pragma unroll
            for (int mt = 0; mt < 4; ++mt) {
                #pragma unroll
                for (int r = 0; r < 4; ++r) {
                    float v = fmaxf(acc[mt][nt][r] + bv, 0.0f);
                    size_t idx = (size_t)(cm0 + mt * 16 + lr + r) * N + cn0 + nt * 16 + lc;
                    Cbf[idx] = f2bf(v);
                }
            }
        }
    } else {
        float bv[2], w3v[2];
        #pragma unroll
        for (int nt = 0; nt < 2; ++nt) {
            bv[nt]  = bias[cn0 + nt * 16 + lc];
            w3v[nt] = w3[cn0 + nt * 16 + lc];
        }
        #pragma unroll
        for (int mt = 0; mt < 4; ++mt) {
            #pragma unroll
            for (int r = 0; r < 4; ++r) {
                float p = 0.0f;
                #pragma unroll
                for (int nt = 0; nt < 2; ++nt)
                    p += fmaxf(acc[mt][nt][r] + bv[nt], 0.0f) * w3v[nt];
                p += __shfl_xor(p, 1);
                p += __shfl_xor(p, 2);
                p += __shfl_xor(p, 4);
                p += __shfl_xor(p, 8);
                if (lc == 0)
                    atomicAdd(&scores[cm0 + mt * 16 + lr + r], p);
            }
        }
    }
}

// ---------------------------------------------------------------------------
// Fused finalize + rank count, 2-D tiled (R10: back to 256 blocks — R7/R9's
// 16-block shape serialized ~16k broadcast LDS ops on 16 CUs, ~35 us).
// Block (bi,bj): builds j-tile keys [bj*256,+256) from sc+b3 in LDS, each
// thread counts kj[j] < key(i) for i = bi*256+t, atomicAdd into posg[i].
// bj==0 blocks also write out_scores. posg zeroed in prep_all.
// ---------------------------------------------------------------------------
__global__ __launch_bounds__(256) void rank_count(
    const float* __restrict__ sc, const float* __restrict__ b3,
    float* __restrict__ out_scores, int* __restrict__ posg)
{
    __shared__ unsigned long long kj[256];
    const int t = threadIdx.x;
    const int bi = blockIdx.x, bj = blockIdx.y;
    const int i = bi * 256 + t;
    const float b3v = b3[0];

    {
        int j = bj * 256 + t;
        kj[t] = sort_key(sc[j] + b3v, j);
    }
    float vi = sc[i] + b3v;
    if (bj == 0) out_scores[i] = vi;
    const unsigned long long mykey = sort_key(vi, i);
    __syncthreads();

    int cnt = 0;
    #pragma unroll 32
    for (int j = 0; j < 256; ++j)
        cnt += (kj[j] < mykey) ? 1 : 0;
    atomicAdd(&posg[i], cnt);
}

// ---------------------------------------------------------------------------
// PAV + fill, single block of 1024 threads (chunked PAV, verified R2-R9).
// ---------------------------------------------------------------------------
__global__ __launch_bounds__(1024) void pav_fill(
    const float* __restrict__ scores, const float* __restrict__ b3,
    const int* __restrict__ posg, float* __restrict__ rank_out, int* nb_ws)
{
    constexpr int n = 4096;
    __shared__ __align__(16) unsigned char lds[65536];
    double* bsum  = (double*)lds;
    float*  svals = (float*)(lds + 32768);
    unsigned short* bstart = (unsigned short*)(lds + 49152);
    unsigned short* plds   = (unsigned short*)(lds + 57344);

    const int tid = threadIdx.x;
    const float b3v = b3[0];

    for (int t = tid; t < n; t += 1024) {
        int p = posg[t];
        svals[p] = scores[t] + b3v;
        plds[t] = (unsigned short)p;
    }
    __syncthreads();

    // ---- Phase A: per-chunk PAV, 64 threads, chunk c = tid ----
    if (tid < 64) {
        const int base = tid << 6;
        int depth = 0;
        double rtsum = 0.0; int rtstart = 0;
        for (int s = 0; s < 64; ++s) {
            int i = base + s;
            double csum = (double)svals[i] - (double)(n - i);   // y_i
            int cs = i;
            const int ce = i + 1;
            while (depth > 0) {
                if (rtsum * (double)(ce - cs) <= csum * (double)(cs - rtstart)) {
                    csum += rtsum; cs = rtstart; depth--;
                    if (depth > 0) {
                        rtsum = bsum[base + depth - 1];
                        rtstart = bstart[base + depth - 1];
                    }
                } else break;
            }
            if (depth > 0) {
                bsum[base + depth - 1] = rtsum;
                bstart[base + depth - 1] = (unsigned short)rtstart;
            }
            rtsum = csum; rtstart = cs; depth++;
        }
        bsum[base + depth - 1] = rtsum;
        bstart[base + depth - 1] = (unsigned short)rtstart;
        if (depth < 64) bstart[base + depth] = 0xFFFFu;   // sentinel
    }
    __syncthreads();

    // ---- Phase B: serial merge of chunk block lists (thread 0) ----
    if (tid == 0) {
        int g = 0;
        double gtsum = 0.0; int gtstart = 0;
        for (int c = 0; c < 64; ++c) {
            const int base = c << 6;
            for (int s = 0; s < 64; ++s) {
                const int r = base + s;
                int cs = bstart[r];
                if (cs == 0xFFFF) break;
                int ce;
                if (s < 63) {
                    int nx = bstart[r + 1];
                    ce = (nx == 0xFFFF) ? base + 64 : nx;
                } else ce = base + 64;
                double csum = bsum[r];
                while (g > 0) {
                    if (gtsum * (double)(ce - cs) <= csum * (double)(cs - gtstart)) {
                        csum += gtsum; cs = gtstart; g--;
                        if (g > 0) { gtsum = bsum[g - 1]; gtstart = bstart[g - 1]; }
                    } else break;
                }
                if (g > 0) {
                    bsum[g - 1] = gtsum;
                    bstart[g - 1] = (unsigned short)gtstart;
                }
                gtsum = csum; gtstart = cs; g++;
            }
        }
        bsum[g - 1] = gtsum;
        bstart[g - 1] = (unsigned short)gtstart;
        __hip_atomic_store(nb_ws, g, __ATOMIC_RELEASE, __HIP_MEMORY_SCOPE_AGENT);
    }
    __syncthreads();
    const int nb = __hip_atomic_load(nb_ws, __ATOMIC_ACQUIRE, __HIP_MEMORY_SCOPE_AGENT);

    // ---- gather: rank[i] = svals[p] - mean(block(p)), coalesced writes ----
    for (int t = tid; t < n; t += 1024) {
        int p = plds[t];
        int lo = 0, hi = nb - 1;
        while (lo < hi) {
            int mid = (lo + hi + 1) >> 1;
            if ((int)bstart[mid] <= p) lo = mid; else hi = mid - 1;
        }
        int bs = bstart[lo];
        int be = (lo + 1 < nb) ? (int)bstart[lo + 1] : n;
        float mean = (float)(bsum[lo] / (double)(be - bs));
        rank_out[t] = svals[p] - mean;
    }
}

// ---------------------------------------------------------------------------
extern "C" void kernel_launch(void* const* d_in, const int* in_sizes, int n_in,
                              void* d_out, int out_size, void* d_ws, size_t ws_size,
                              hipStream_t stream) {
    const float* x  = (const float*)d_in[0];
    const float* W1 = (const float*)d_in[1];
    const float* b1 = (const float*)d_in[2];
    const float* W2 = (const float*)d_in[3];
    const float* b2 = (const float*)d_in[4];
    const float* W3 = (const float*)d_in[5];
    const float* b3 = (const float*)d_in[6];
    float* out = (float*)d_out;   // [0,4096): rank, [4096,8192): scores

    const int B = 4096, D_IN = 512, H = 2048;

    char* ws = (char*)d_ws;
    unsigned short* h1  = (unsigned short*)(ws);                    // 16 MB bf16
    unsigned short* xb  = (unsigned short*)(ws + (16u << 20));      //  4 MB bf16
    unsigned short* W1t = (unsigned short*)(ws + (20u << 20));      //  2 MB bf16 [N,K]
    unsigned short* W2t = (unsigned short*)(ws + (22u << 20));      //  8 MB bf16 [N,K]
    float*          sc  = (float*)(ws + (30u << 20));               // 16 KB
    int*            posg= (int*)(ws + (30u << 20) + 16384);         // 16 KB
    int*            nb  = (int*)(ws + (30u << 20) + 32768);

    // 1) fused prep: convert x, transpose W1/W2, zero sc+posg.
    prep_all<<<2305, 256, 0, stream>>>(x, xb, W1, W1t, W2, W2t, sc, posg);

    // 2) GEMM1: h1 = relu(x @ W1 + b1), bf16. M=4096 N=2048 K=512.
    gemm_bf16_mfma<0><<<dim3(H / 128, B / 128), 512, 0, stream>>>(
        xb, W1t, b1, h1, nullptr, nullptr, B, H, D_IN);
    // 3) GEMM2 fused with layer-3: scores += relu(h1@W2+b2) @ W3.
    gemm_bf16_mfma<1><<<dim3(H / 128, B / 128), 512, 0, stream>>>(
        h1, W2t, b2, nullptr, W3, sc, B, H, H);

    // 4) fused finalize + rank count (256 blocks, keys from sc in-block).
    rank_count<<<dim3(B / 256, B / 256), 256, 0, stream>>>(sc, b3, out + B, posg);
    // 5) PAV + fill.
    pav_fill<<<1, 1024, 0, stream>>>(sc, b3, posg, out, nb);
}

// Round 12
// 178.603 us; speedup vs baseline: 1.2021x; 1.0246x over previous
//
#include <hip/hip_runtime.h>
#include <hip/hip_bf16.h>

typedef float f32x4 __attribute__((ext_vector_type(4)));
typedef __bf16 bf16x8 __attribute__((ext_vector_type(8)));

#define AS3(p) ((__attribute__((address_space(3))) void*)(p))
#define AS1(p) ((const __attribute__((address_space(1))) void*)(p))

__device__ __forceinline__ unsigned short f2bf(float f) {
    unsigned u = __float_as_uint(f);
    return (unsigned short)((u + 0x7fffu + ((u >> 16) & 1u)) >> 16);  // RNE
}

__device__ __forceinline__ unsigned long long sort_key(float v, int idx) {
    unsigned ub = __float_as_uint(v);
    unsigned m  = (ub & 0x80000000u) ? ~ub : (ub | 0x80000000u);  // asc map
    return ((unsigned long long)(~m) << 12) | (unsigned)idx;      // desc, stable
}

// ---------------------------------------------------------------------------
// Fused prep: one dispatch.
//   blocks [0,1024):      x fp32 -> bf16
//   blocks [1024,2304):   W1/W2 transpose+convert (64x64 tiles)
//   block  2304:          zero scores accumulator + posg
// ---------------------------------------------------------------------------
__global__ __launch_bounds__(256) void prep_all(
    const float* __restrict__ x, unsigned short* __restrict__ xb,
    const float* __restrict__ W1, unsigned short* __restrict__ W1t,
    const float* __restrict__ W2, unsigned short* __restrict__ W2t,
    float* __restrict__ sc, int* __restrict__ posg)
{
    __shared__ float tile[64][65];
    const int bx = blockIdx.x;
    const int t = threadIdx.x;

    if (bx < 1024) {                       // convert x
        int i = bx * 2048 + t * 8;
        float4 v0 = *(const float4*)(x + i);
        float4 v1 = *(const float4*)(x + i + 4);
        ushort4 o0 = { f2bf(v0.x), f2bf(v0.y), f2bf(v0.z), f2bf(v0.w) };
        ushort4 o1 = { f2bf(v1.x), f2bf(v1.y), f2bf(v1.z), f2bf(v1.w) };
        *(ushort4*)(xb + i)     = o0;
        *(ushort4*)(xb + i + 4) = o1;
        return;
    }
    if (bx == 2304) {                      // zero sc + posg
        float4 z = {0.f, 0.f, 0.f, 0.f};
        int4 zi = {0, 0, 0, 0};
        #pragma unroll
        for (int i = 0; i < 4; ++i) {
            *(float4*)(sc + t * 16 + i * 4)  = z;
            *(int4*)(posg + t * 16 + i * 4)  = zi;
        }
        return;
    }
    // transpose tiles
    int idx = bx - 1024;
    int ty = idx >> 5;                     // 0..39
    int txi = idx & 31;                    // 0..31
    const float* W; unsigned short* Wt; int K, N, by;
    if (ty < 8) { W = W1; Wt = W1t; K = 512;  N = 2048; by = ty; }
    else        { W = W2; Wt = W2t; K = 2048; N = 2048; by = ty - 8; }

    const int col4 = t & 15;
    const int row  = t >> 4;
    #pragma unroll
    for (int i = 0; i < 4; ++i) {
        int r = row + i * 16;
        float4 v = *(const float4*)(W + (size_t)(by * 64 + r) * N + txi * 64 + col4 * 4);
        tile[r][col4 * 4 + 0] = v.x;
        tile[r][col4 * 4 + 1] = v.y;
        tile[r][col4 * 4 + 2] = v.z;
        tile[r][col4 * 4 + 3] = v.w;
    }
    __syncthreads();
    #pragma unroll
    for (int i = 0; i < 4; ++i) {
        int r = row + i * 16;
        ushort4 o = { f2bf(tile[col4 * 4 + 0][r]), f2bf(tile[col4 * 4 + 1][r]),
                      f2bf(tile[col4 * 4 + 2][r]), f2bf(tile[col4 * 4 + 3][r]) };
        *(ushort4*)(Wt + (size_t)(txi * 64 + r) * K + by * 64 + col4 * 4) = o;
    }
}

// ---------------------------------------------------------------------------
// bf16 MFMA GEMM, 128x128 tile, BK=128 (R12: halve drain count again vs R10's
// BK=64; drain count is the verified lever from R9->R10). 512 threads =
// 8 waves (wm 2x64, wn 4x32), LDS 64 KB, 2 blocks/CU (same as R10, which R7
// showed is not wave-starved at 16 waves/CU).
// Swizzle: LDS(r,c) = global(r, c ^ (r&15)), c = 16B chunk (16 per 256B row).
// Frag reads: per quarter-group chunk = (s*4+g)^m -> bank (c%8)*4, each value
// hit exactly twice (2-way = free, m136). All address math lane-only.
// MODE 0: C = relu(A@Bt^T+bias) bf16.  MODE 1: fused layer-3 rank-1 epilogue.
// ---------------------------------------------------------------------------
template <int MODE>
__global__ __launch_bounds__(512, 4) void gemm_bf16_mfma(
    const unsigned short* __restrict__ A, const unsigned short* __restrict__ Bt,
    const float* __restrict__ bias, unsigned short* __restrict__ Cbf,
    const float* __restrict__ w3, float* __restrict__ scores,
    int M, int N, int K)
{
    __shared__ unsigned short As[128 * 128];   // 32 KB
    __shared__ unsigned short Bs[128 * 128];   // 32 KB

    const int tid = threadIdx.x;
    const int wave = tid >> 6, lane = tid & 63;
    const int bn = blockIdx.x, bm = blockIdx.y;
    const int wm = (wave & 1) * 64, wn = (wave >> 1) * 32;

    const unsigned short* Ablk = A  + (size_t)(bm * 128) * K;
    const unsigned short* Bblk = Bt + (size_t)(bn * 128) * K;

    const int rl4 = lane >> 4;          // 0..3 (row within 4-row segment)
    const int ch  = lane & 15;          // chunk slot

    f32x4 acc[4][2] = {};

    for (int k0 = 0; k0 < K; k0 += 128) {
        #pragma unroll
        for (int s2 = 0; s2 < 4; ++s2) {        // wave stages A+B rows [wave*16,+16)
            int r0 = wave * 16 + s2 * 4;
            int ra = r0 + rl4;
            int gc = (ch ^ (ra & 15)) * 8;      // swizzled global chunk
            __builtin_amdgcn_global_load_lds(
                AS1(Ablk + (size_t)ra * K + k0 + gc), AS3(As + r0 * 128), 16, 0, 0);
            __builtin_amdgcn_global_load_lds(
                AS1(Bblk + (size_t)ra * K + k0 + gc), AS3(Bs + r0 * 128), 16, 0, 0);
        }
        __syncthreads();

        #pragma unroll
        for (int s = 0; s < 4; ++s) {           // four 16x16x32 k-steps
            const int rsw = ((s * 4 + (lane >> 4)) ^ (lane & 15)) * 8;
            bf16x8 a[4], b[2];
            #pragma unroll
            for (int mt = 0; mt < 4; ++mt)
                a[mt] = *(const bf16x8*)(As + (wm + mt * 16 + (lane & 15)) * 128 + rsw);
            #pragma unroll
            for (int nt = 0; nt < 2; ++nt)
                b[nt] = *(const bf16x8*)(Bs + (wn + nt * 16 + (lane & 15)) * 128 + rsw);
            #pragma unroll
            for (int mt = 0; mt < 4; ++mt)
                #pragma unroll
                for (int nt = 0; nt < 2; ++nt)
                    acc[mt][nt] = __builtin_amdgcn_mfma_f32_16x16x32_bf16(
                        a[mt], b[nt], acc[mt][nt], 0, 0, 0);
        }
        __syncthreads();
    }

    // Epilogue. C/D frag: col = lane&15, row = (lane>>4)*4 + reg  [m89]
    const int cm0 = bm * 128 + wm;
    const int cn0 = bn * 128 + wn;
    const int lc = lane & 15;
    const int lr = (lane >> 4) * 4;

    if (MODE == 0) {
        #pragma unroll
        for (int nt = 0; nt < 2; ++nt) {
            float bv = bias[cn0 + nt * 16 + lc];
            #pragma unroll
            for (int mt = 0; mt < 4; ++mt)
                #pragma unroll
                for (int r = 0; r < 4; ++r) {
                    float v = fmaxf(acc[mt][nt][r] + bv, 0.0f);
                    size_t idx = (size_t)(cm0 + mt * 16 + lr + r) * N + cn0 + nt * 16 + lc;
                    Cbf[idx] = f2bf(v);
                }
        }
    } else {
        float bv[2], w3v[2];
        #pragma unroll
        for (int nt = 0; nt < 2; ++nt) {
            bv[nt]  = bias[cn0 + nt * 16 + lc];
            w3v[nt] = w3[cn0 + nt * 16 + lc];
        }
        #pragma unroll
        for (int mt = 0; mt < 4; ++mt)
            #pragma unroll
            for (int r = 0; r < 4; ++r) {
                float p = 0.0f;
                #pragma unroll
                for (int nt = 0; nt < 2; ++nt)
                    p += fmaxf(acc[mt][nt][r] + bv[nt], 0.0f) * w3v[nt];
                p += __shfl_xor(p, 1);
                p += __shfl_xor(p, 2);
                p += __shfl_xor(p, 4);
                p += __shfl_xor(p, 8);
                if (lc == 0)
                    atomicAdd(&scores[cm0 + mt * 16 + lr + r], p);
            }
    }
}

// ---------------------------------------------------------------------------
// Fused finalize + rank count, 2-D tiled (256 blocks — R10 shape, ~4 us).
// ---------------------------------------------------------------------------
__global__ __launch_bounds__(256) void rank_count(
    const float* __restrict__ sc, const float* __restrict__ b3,
    float* __restrict__ out_scores, int* __restrict__ posg)
{
    __shared__ unsigned long long kj[256];
    const int t = threadIdx.x;
    const int bi = blockIdx.x, bj = blockIdx.y;
    const int i = bi * 256 + t;
    const float b3v = b3[0];

    {
        int j = bj * 256 + t;
        kj[t] = sort_key(sc[j] + b3v, j);
    }
    float vi = sc[i] + b3v;
    if (bj == 0) out_scores[i] = vi;
    const unsigned long long mykey = sort_key(vi, i);
    __syncthreads();

    int cnt = 0;
    #pragma unroll 32
    for (int j = 0; j < 256; ++j)
        cnt += (kj[j] < mykey) ? 1 : 0;
    atomicAdd(&posg[i], cnt);
}

// ---------------------------------------------------------------------------
// PAV + fill, single block of 1024 threads (chunked PAV, verified R2-R10).
// ---------------------------------------------------------------------------
__global__ __launch_bounds__(1024) void pav_fill(
    const float* __restrict__ scores, const float* __restrict__ b3,
    const int* __restrict__ posg, float* __restrict__ rank_out, int* nb_ws)
{
    constexpr int n = 4096;
    __shared__ __align__(16) unsigned char lds[65536];
    double* bsum  = (double*)lds;
    float*  svals = (float*)(lds + 32768);
    unsigned short* bstart = (unsigned short*)(lds + 49152);
    unsigned short* plds   = (unsigned short*)(lds + 57344);

    const int tid = threadIdx.x;
    const float b3v = b3[0];

    for (int t = tid; t < n; t += 1024) {
        int p = posg[t];
        svals[p] = scores[t] + b3v;
        plds[t] = (unsigned short)p;
    }
    __syncthreads();

    // ---- Phase A: per-chunk PAV, 64 threads, chunk c = tid ----
    if (tid < 64) {
        const int base = tid << 6;
        int depth = 0;
        double rtsum = 0.0; int rtstart = 0;
        for (int s = 0; s < 64; ++s) {
            int i = base + s;
            double csum = (double)svals[i] - (double)(n - i);   // y_i
            int cs = i;
            const int ce = i + 1;
            while (depth > 0) {
                if (rtsum * (double)(ce - cs) <= csum * (double)(cs - rtstart)) {
                    csum += rtsum; cs = rtstart; depth--;
                    if (depth > 0) {
                        rtsum = bsum[base + depth - 1];
                        rtstart = bstart[base + depth - 1];
                    }
                } else break;
            }
            if (depth > 0) {
                bsum[base + depth - 1] = rtsum;
                bstart[base + depth - 1] = (unsigned short)rtstart;
            }
            rtsum = csum; rtstart = cs; depth++;
        }
        bsum[base + depth - 1] = rtsum;
        bstart[base + depth - 1] = (unsigned short)rtstart;
        if (depth < 64) bstart[base + depth] = 0xFFFFu;   // sentinel
    }
    __syncthreads();

    // ---- Phase B: serial merge of chunk block lists (thread 0) ----
    if (tid == 0) {
        int g = 0;
        double gtsum = 0.0; int gtstart = 0;
        for (int c = 0; c < 64; ++c) {
            const int base = c << 6;
            for (int s = 0; s < 64; ++s) {
                const int r = base + s;
                int cs = bstart[r];
                if (cs == 0xFFFF) break;
                int ce;
                if (s < 63) {
                    int nx = bstart[r + 1];
                    ce = (nx == 0xFFFF) ? base + 64 : nx;
                } else ce = base + 64;
                double csum = bsum[r];
                while (g > 0) {
                    if (gtsum * (double)(ce - cs) <= csum * (double)(cs - gtstart)) {
                        csum += gtsum; cs = gtstart; g--;
                        if (g > 0) { gtsum = bsum[g - 1]; gtstart = bstart[g - 1]; }
                    } else break;
                }
                if (g > 0) {
                    bsum[g - 1] = gtsum;
                    bstart[g - 1] = (unsigned short)gtstart;
                }
                gtsum = csum; gtstart = cs; g++;
            }
        }
        bsum[g - 1] = gtsum;
        bstart[g - 1] = (unsigned short)gtstart;
        __hip_atomic_store(nb_ws, g, __ATOMIC_RELEASE, __HIP_MEMORY_SCOPE_AGENT);
    }
    __syncthreads();
    const int nb = __hip_atomic_load(nb_ws, __ATOMIC_ACQUIRE, __HIP_MEMORY_SCOPE_AGENT);

    // ---- gather: rank[i] = svals[p] - mean(block(p)), coalesced writes ----
    for (int t = tid; t < n; t += 1024) {
        int p = plds[t];
        int lo = 0, hi = nb - 1;
        while (lo < hi) {
            int mid = (lo + hi + 1) >> 1;
            if ((int)bstart[mid] <= p) lo = mid; else hi = mid - 1;
        }
        int bs = bstart[lo];
        int be = (lo + 1 < nb) ? (int)bstart[lo + 1] : n;
        float mean = (float)(bsum[lo] / (double)(be - bs));
        rank_out[t] = svals[p] - mean;
    }
}

// ---------------------------------------------------------------------------
extern "C" void kernel_launch(void* const* d_in, const int* in_sizes, int n_in,
                              void* d_out, int out_size, void* d_ws, size_t ws_size,
                              hipStream_t stream) {
    const float* x  = (const float*)d_in[0];
    const float* W1 = (const float*)d_in[1];
    const float* b1 = (const float*)d_in[2];
    const float* W2 = (const float*)d_in[3];
    const float* b2 = (const float*)d_in[4];
    const float* W3 = (const float*)d_in[5];
    const float* b3 = (const float*)d_in[6];
    float* out = (float*)d_out;   // [0,4096): rank, [4096,8192): scores

    const int B = 4096, D_IN = 512, H = 2048;

    char* ws = (char*)d_ws;
    unsigned short* h1  = (unsigned short*)(ws);                    // 16 MB bf16
    unsigned short* xb  = (unsigned short*)(ws + (16u << 20));      //  4 MB bf16
    unsigned short* W1t = (unsigned short*)(ws + (20u << 20));      //  2 MB bf16 [N,K]
    unsigned short* W2t = (unsigned short*)(ws + (22u << 20));      //  8 MB bf16 [N,K]
    float*          sc  = (float*)(ws + (30u << 20));               // 16 KB
    int*            posg= (int*)(ws + (30u << 20) + 16384);         // 16 KB
    int*            nb  = (int*)(ws + (30u << 20) + 32768);

    // 1) fused prep: convert x, transpose W1/W2, zero sc+posg.
    prep_all<<<2305, 256, 0, stream>>>(x, xb, W1, W1t, W2, W2t, sc, posg);

    // 2) GEMM1: h1 = relu(x @ W1 + b1), bf16. M=4096 N=2048 K=512.
    gemm_bf16_mfma<0><<<dim3(H / 128, B / 128), 512, 0, stream>>>(
        xb, W1t, b1, h1, nullptr, nullptr, B, H, D_IN);
    // 3) GEMM2 fused with layer-3: scores += relu(h1@W2+b2) @ W3.
    gemm_bf16_mfma<1><<<dim3(H / 128, B / 128), 512, 0, stream>>>(
        h1, W2t, b2, nullptr, W3, sc, B, H, H);

    // 4) fused finalize + rank count (256 blocks, keys from sc in-block).
    rank_count<<<dim3(B / 256, B / 256), 256, 0, stream>>>(sc, b3, out + B, posg);
    // 5) PAV + fill.
    pav_fill<<<1, 1024, 0, stream>>>(sc, b3, posg, out, nb);
}